// Round 6
// baseline (13558.589 us; speedup 1.0000x reference)
//
#include <hip/hip_runtime.h>
#include <hip/hip_bf16.h>

// MultilayerGRU: B=32 S=512 I=H=O=1024 L=3.
// Round 10: remove the per-step L2 inv entirely (per-XCD staging mirror).
//  Theory: agent-acquire's buffer_inv sc1 flash-invalidates the whole 4MB L2;
//  the tag walk (~65k lines) costs 3-13us of L2-pipe occupancy SERIALLY in
//  every step, invisible to all SQ/TCC counters. R3->R4 flatness (32 invs ->
//  1 inv) is explained by walk merging; no round removed the walk itself.
//  New scheme:
//   - producers still publish h via relaxed sc1 stores (write-through to L3)
//   - after the global barrier, each XCD's WGs cooperatively copy the 3
//     freshly-published 128KB slabs (12KB/WG, sc1 reads) into a per-XCD
//     staging MIRROR with plain stores -> lines live in the LOCAL L2, which
//     is hardware-coherent within the XCD. Consumers read the mirror with
//     plain cached loads. NO L2 inv anywhere; x + instruction lines stay
//     warm in L2 across steps.
//   - per-CU L1 flash-inv (plain buffer_inv, proven R4) guards stale L1
//     copies of mirror addresses (reuse period = 2 steps).
//   - XCD-local barrier: syncthreads (drains all waves' staging stores) ->
//     tid0 atomicAdd xbar[xcd] -> poll >= T*round -> buffer_inv -> sync.
//   - XCD membership via s_getreg(HW_REG_XCC_ID); per-XCD ticket via one
//     atomicAdd at start (robust to any WG->XCD distribution).
//  Kept from earlier rounds: template<F32M> split, x-prefetch in barrier
//  window, clds read-then-zero, master+gen-tree global barrier.

#define NB 32
#define NS 512
#define NI 1024
#define NH 1024
#define NL 3
#define NO 1024

#define WGN 256
#define BLK 512
#define SLOTS 12
#define RPB 2096                 // weight row pitch bytes; 524 dwords == 12 mod 32 -> 2-way max (free)
#define ZROW 72                  // zero-row index
#define COFF (73 * RPB)          // 153,008
#define CPITCH 33                // 33 dwords == 1 mod 32 -> conflict-free
#define SHTK (COFF + 48 * CPITCH * 4)   // 159,344: 16B scratch for ticket/T broadcast
#define LDSB (SHTK + 16)                // 159,360 <= 163,840

// gflags dword-index layout (each logical flag on its own 128B line):
#define GENB   (WGN * 32)            // 8192: 16 gen-copy lines
#define CNTB   (GENB + 16 * 32)      // 8704: per-XCD ticket counters (8 lines)
#define XBARB  (CNTB + 8 * 32)       // 8960: per-XCD local-barrier counters (8 lines)
#define GFL_N  (XBARB + 8 * 32)      // 9216

#define STAGE_U32 196608             // 6 slabs * 32768 u32 = 768 KB per XCD

using short8 = __attribute__((ext_vector_type(8))) short;
using floatx4 = __attribute__((ext_vector_type(4))) float;

static __device__ __forceinline__ float bf2f(unsigned short u) {
    union { unsigned int i; float f; } v;
    v.i = ((unsigned int)u) << 16;
    return v.f;
}

static __device__ __forceinline__ unsigned short f2bf(float f) {
    __hip_bfloat16 h = __float2bfloat16(f);   // RNE
    union { __hip_bfloat16 h; unsigned short u; } v;
    v.h = h;
    return v.u;
}

static __device__ __forceinline__ void load8h(const unsigned short* p, float w[8]) {
    uint4 q = *(const uint4*)p;
    unsigned int u[4] = {q.x, q.y, q.z, q.w};
#pragma unroll
    for (int i = 0; i < 4; ++i) {
        w[2*i]   = __uint_as_float(u[i] << 16);
        w[2*i+1] = __uint_as_float(u[i] & 0xffff0000u);
    }
}

static __device__ __forceinline__ void load8f(const float* p, float w[8]) {
    float4 a = *(const float4*)p;
    float4 b = *(const float4*)(p + 4);
    w[0]=a.x; w[1]=a.y; w[2]=a.z; w[3]=a.w;
    w[4]=b.x; w[5]=b.y; w[6]=b.z; w[7]=b.w;
}

static __device__ __forceinline__ int xcc_id() {
    unsigned v;
    asm volatile("s_getreg_b32 %0, hwreg(20, 0, 32)" : "=s"(v));   // HW_REG_XCC_ID
    return (int)(v & 7);
}

// ---------------- dtype detection ----------------
__global__ void detect_kernel(const unsigned int* __restrict__ xw, int* __restrict__ flag) {
    __shared__ int cnt[256];
    int c = 0;
    for (int i = threadIdx.x; i < 1024; i += 256) {
        unsigned int e = (xw[i] >> 7) & 0xFFu;
        if (e >= 0x78u && e <= 0x84u) c++;
    }
    cnt[threadIdx.x] = c;
    __syncthreads();
    if (threadIdx.x == 0) {
        int s = 0;
        for (int i = 0; i < 256; ++i) s += cnt[i];
        *flag = (s < 512) ? 1 : 0;
    }
}

// ---------------- init: h0 -> act parity-1 packed (hi<<16|lo); zero flags ----
__global__ void init_act(const void* __restrict__ h0,
                         unsigned int* __restrict__ act,
                         unsigned int* __restrict__ gflags,
                         const int* __restrict__ flagp) {
    const int f32m = *flagp;
    const int idx = blockIdx.x * 256 + threadIdx.x;  // l*32768 + b*1024 + j
    if (idx < GFL_N) gflags[idx] = 0u;
    if (idx >= NL * NB * NH) return;
    const int l = idx >> 15;
    const int b = (idx >> 10) & 31;
    const int j = idx & 1023;
    const size_t src = (size_t)b * NL * NH + (size_t)l * NH + j;
    float v = f32m ? ((const float*)h0)[src] : bf2f(((const unsigned short*)h0)[src]);
    unsigned short hi = f2bf(v);
    unsigned short lo = f2bf(v - bf2f(hi));
    const size_t dst = ((size_t)(l * 2 + 1) * NB + b) * NH + j;   // parity 1
    act[dst] = ((unsigned int)hi << 16) | lo;
}

// ---------------- persistent pipeline kernel (templated on dtype) ----------
template<int F32M>
__global__ __launch_bounds__(BLK, 2) void gru_persist(
    const void* __restrict__ x,
    const void* __restrict__ Wzi_, const void* __restrict__ Wzh_, const void* __restrict__ bzh_,
    const void* __restrict__ Wri_, const void* __restrict__ Wrh_, const void* __restrict__ brh_,
    const void* __restrict__ Wgi_, const void* __restrict__ Wgh_, const void* __restrict__ bgh_,
    void* __restrict__ dout,
    unsigned int* __restrict__ act,
    unsigned int* __restrict__ stage,
    float* __restrict__ stfin,
    const int* __restrict__ flagp,
    unsigned int* __restrict__ gflags)
{
    if (*flagp != F32M) return;    // wrong-dtype instantiation: exit fast

    extern __shared__ char lds[];
    float* clds = (float*)(lds + COFF);
    int* sh_tk = (int*)(lds + SHTK);

    const int tid  = threadIdx.x;
    const int wg   = blockIdx.x;
    const int lane = tid & 63;
    const int wid  = tid >> 6;          // 0..7
    const int Mtile = wid & 1;
    const int khalf = wid >> 1;         // 0..3 -> 256-col K slice
    const int n16  = lane & 15;
    const int q4   = lane >> 4;

    const int slot0 = wg * SLOTS;
    const int myxcd = xcc_id();
    unsigned int* const stageX = stage + (size_t)myxcd * STAGE_U32;

    // per-XCD ticket (once)
    if (tid == 0)
        sh_tk[0] = (int)__hip_atomic_fetch_add(&gflags[CNTB + myxcd * 32], 1u,
                                               __ATOMIC_RELAXED, __HIP_MEMORY_SCOPE_AGENT);

    // ---- preload weights into LDS (bf16); zero clds once ----
    {
        const void* Wmats[6] = {Wzi_, Wzh_, Wri_, Wrh_, Wgi_, Wgh_};
        if (F32M) {
            for (int idx = tid; idx < 72 * 256; idx += BLK) {
                const int r = idx >> 8, c4 = (idx & 255) * 4;
                const int slot = slot0 + r / 6, g = r % 6;
                const int layer = slot >> 10, j = slot & 1023;
                const float* src = (const float*)Wmats[g] + (size_t)layer * NH * NI + (size_t)j * NI + c4;
                float4 f = *(const float4*)src;
                unsigned short* dst = (unsigned short*)(lds + r * RPB + c4 * 2);
                dst[0] = f2bf(f.x); dst[1] = f2bf(f.y); dst[2] = f2bf(f.z); dst[3] = f2bf(f.w);
            }
        } else {
            for (int idx = tid; idx < 72 * 128; idx += BLK) {
                const int r = idx >> 7, c8 = (idx & 127) * 8;
                const int slot = slot0 + r / 6, g = r % 6;
                const int layer = slot >> 10, j = slot & 1023;
                const unsigned short* src = (const unsigned short*)Wmats[g] + (size_t)layer * NH * NI + (size_t)j * NI + c8;
                *(uint4*)(lds + r * RPB + c8 * 2) = *(const uint4*)src;
            }
        }
        unsigned int* z = (unsigned int*)(lds + ZROW * RPB);
        for (int c = tid; c < RPB / 4; c += BLK) z[c] = 0u;
        for (int i = tid; i < 48 * CPITCH; i += BLK) clds[i] = 0.f;   // one-time
    }

    // ---- epilogue thread state (tid < 384): biases + register h_prev ----
    int eci = 0, eb = 0, elg = 0, ej = 0;
    float ebz = 0.f, ebr = 0.f, ebg = 0.f, ehp = 0.f;
    if (tid < NB * SLOTS) {
        eci = tid % SLOTS; eb = tid / SLOTS;
        const int slot = slot0 + eci;
        elg = slot >> 10; ej = slot & 1023;
        const size_t bidx = (size_t)elg * NH + ej;
        if (F32M) {
            ebz = ((const float*)bzh_)[bidx];
            ebr = ((const float*)brh_)[bidx];
            ebg = ((const float*)bgh_)[bidx];
        } else {
            ebz = bf2f(((const unsigned short*)bzh_)[bidx]);
            ebr = bf2f(((const unsigned short*)brh_)[bidx]);
            ebg = bf2f(((const unsigned short*)bgh_)[bidx]);
        }
    }

    // ---- layer groups (slot range may straddle one layer boundary) ----
    const int lay0 = slot0 >> 10;
    const int lay1 = (slot0 + SLOTS - 1) >> 10;
    const int ngroups = (lay0 == lay1) ? 1 : 2;
    const int n0 = (ngroups == 1) ? SLOTS : (1024 - (slot0 & 1023));

    const bool isl0 = (lay0 == 0);
    const int mb = Mtile * 16 + n16;

    // x prefetch registers (phase-0 A-frags for layer-0 groups)
    short8 XH[8], XL[8];
    auto xprefetch = [&](int t) {
        if (F32M) {
            const float* xb = (const float*)x + ((size_t)mb * NS + t) * NI + khalf * 256 + q4 * 8;
#pragma unroll
            for (int ks = 0; ks < 8; ++ks) {
                float f[8];
                load8f(xb + ks * 32, f);
#pragma unroll
                for (int e = 0; e < 8; ++e) {
                    unsigned short h = f2bf(f[e]);
                    XH[ks][e] = (short)h;
                    XL[ks][e] = (short)f2bf(f[e] - bf2f(h));
                }
            }
        } else {
            const unsigned short* xb = (const unsigned short*)x + ((size_t)mb * NS + t) * NI + khalf * 256 + q4 * 8;
#pragma unroll
            for (int ks = 0; ks < 8; ++ks)
                XH[ks] = *(const short8*)(xb + ks * 32);
        }
    };

    __syncthreads();                 // broadcast ticket; weights visible
    const int myticket = sh_tk[0];
    int myT = 1;                     // set for real at s == -1

    // s = -1 is a staging-only prologue round (stages all 6 init slabs).
    for (int s = -1; s < NS + NL - 1; ++s) {
        if (s >= 0) {
            floatx4 acc[3];
#pragma unroll
            for (int nt = 0; nt < 3; ++nt) acc[nt] = (floatx4){0.f, 0.f, 0.f, 0.f};

            for (int grp = 0; grp < ngroups; ++grp) {
                const int lg = (grp == 0) ? lay0 : lay1;
                const int t = s - lg;
                if (t < 0 || t >= NS) continue;
                const int ntLo = (grp == 0) ? 0 : ((4 * n0) >> 4);
                const int ntHi = (grp == 0) ? (ngroups == 1 ? 2 : ((4 * n0) >> 4) - 1) : 2;

                for (int phase = 0; phase < 2; ++phase) {
                    int brow[3];
#pragma unroll
                    for (int nt = 0; nt < 3; ++nt) {
                        const int v = nt * 16 + n16;
                        const int ci = v >> 2, g = v & 3;
                        int r;
                        if (phase == 0) r = (g == 3) ? ZROW : ci * 6 + ((g == 2) ? 4 : g * 2);
                        else            r = (g == 2) ? ZROW : ci * 6 + ((g == 3) ? 5 : g * 2 + 1);
                        brow[nt] = r;
                    }

                    const bool isx = (phase == 0 && lg == 0);
                    const bool dolo = isx ? (F32M != 0) : true;

                    short8 AH[8], AL[8];
                    if (isx) {
                        // prefetched during previous barrier window
#pragma unroll
                        for (int ks = 0; ks < 8; ++ks) { AH[ks] = XH[ks]; if (F32M) AL[ks] = XL[ks]; }
                    } else {
                        const int src_l = (phase == 0) ? lg - 1 : lg;
                        const int src_p = (phase == 0) ? (t & 1) : ((t - 1) & 1);
                        const size_t ab = ((size_t)(src_l * 2 + src_p) * NB + mb) * NH + khalf * 256 + q4 * 8;
                        // plain cached loads from the per-XCD staging mirror
                        // (lines written by same-XCD WGs -> local-L2 coherent)
                        const uint4* ap = (const uint4*)(stageX + ab);
                        uint4 qq[16];
#pragma unroll
                        for (int ks = 0; ks < 8; ++ks) {
                            qq[2*ks]   = ap[ks * 8];
                            qq[2*ks+1] = ap[ks * 8 + 1];
                        }
#pragma unroll
                        for (int ks = 0; ks < 8; ++ks) {
                            unsigned int c[8] = {qq[2*ks].x, qq[2*ks].y, qq[2*ks].z, qq[2*ks].w,
                                                 qq[2*ks+1].x, qq[2*ks+1].y, qq[2*ks+1].z, qq[2*ks+1].w};
#pragma unroll
                            for (int e = 0; e < 8; ++e) {
                                AH[ks][e] = (short)(c[e] >> 16);
                                AL[ks][e] = (short)(c[e] & 0xffffu);
                            }
                        }
                    }

#pragma unroll
                    for (int ks = 0; ks < 8; ++ks) {
                        const int k0 = khalf * 256 + ks * 32;
#pragma unroll
                        for (int nt = 0; nt < 3; ++nt) {
                            if (nt < ntLo || nt > ntHi) continue;
                            const short8 bf = *(const short8*)(lds + brow[nt] * RPB + k0 * 2 + q4 * 16);
                            acc[nt] = __builtin_amdgcn_mfma_f32_16x16x32_bf16(AH[ks], bf, acc[nt], 0, 0, 0);
                            if (dolo)
                                acc[nt] = __builtin_amdgcn_mfma_f32_16x16x32_bf16(AL[ks], bf, acc[nt], 0, 0, 0);
                        }
                    }
                }
            }

            // dump accumulators (C/D: col=lane&15, row=q4*4+reg)
            {
                const int mbase = Mtile * 16 + q4 * 4;
#pragma unroll
                for (int nt = 0; nt < 3; ++nt) {
                    const int vcol = nt * 16 + n16;
#pragma unroll
                    for (int r = 0; r < 4; ++r)
                        atomicAdd(&clds[vcol * CPITCH + mbase + r], acc[nt][r]);
                }
            }
            __syncthreads();

            // epilogue: one thread per (col, batch); read-then-zero its 4 slots
            if (tid < NB * SLOTS) {
                const int t = s - elg;
                if (t >= 0 && t < NS) {
                    const float zp = clds[(eci * 4 + 0) * CPITCH + eb];
                    const float rp = clds[(eci * 4 + 1) * CPITCH + eb];
                    const float gi = clds[(eci * 4 + 2) * CPITCH + eb];
                    const float gh = clds[(eci * 4 + 3) * CPITCH + eb];
                    clds[(eci * 4 + 0) * CPITCH + eb] = 0.f;
                    clds[(eci * 4 + 1) * CPITCH + eb] = 0.f;
                    clds[(eci * 4 + 2) * CPITCH + eb] = 0.f;
                    clds[(eci * 4 + 3) * CPITCH + eb] = 0.f;
                    float hp;
                    if (t == 0) {
                        const size_t hoff = ((size_t)(elg * 2 + 1) * NB + eb) * NH + ej;
                        const unsigned int pv = stageX[hoff];   // staged at s = -1
                        hp = bf2f((unsigned short)(pv >> 16)) + bf2f((unsigned short)(pv & 0xffffu));
                    } else {
                        hp = ehp;
                    }
                    const float z = 1.f / (1.f + expf(-(zp + ebz)));
                    const float r = 1.f / (1.f + expf(-(rp + ebr)));
                    const float g = tanhf(gi + r * (gh + ebg));
                    const float hn = z * hp + (1.f - z) * g;
                    ehp = hn;
                    const unsigned short hi = f2bf(hn);
                    const unsigned short lo = f2bf(hn - bf2f(hi));
                    const size_t woff = ((size_t)(elg * 2 + (t & 1)) * NB + eb) * NH + ej;
                    // sc1 write-through store: lands in L3, never dirty in L2
                    __hip_atomic_store(&act[woff], ((unsigned int)hi << 16) | lo,
                                       __ATOMIC_RELAXED, __HIP_MEMORY_SCOPE_AGENT);
                    if (elg == 2) {
                        const size_t o = ((size_t)eb * NS + t) * NO + ej;
                        if (F32M) ((float*)dout)[o] = hn;
                        else      ((unsigned short*)dout)[o] = f2bf(hn);
                    }
                    if (t == NS - 1)
                        stfin[((size_t)elg * NB + eb) * NH + ej] = hn;
                }
            }
        }

        // ---- global barrier: arrival -> (x prefetch overlap) -> master/gen
        __syncthreads();   // drains each wave's sc1 stores (vmcnt 0) before publish
        if (tid == 0)
            __hip_atomic_store(&gflags[wg * 32], (unsigned int)(s + 2),
                               __ATOMIC_RELAXED, __HIP_MEMORY_SCOPE_AGENT);

        // overlap next-step x load+convert with the barrier hops (x read-only)
        if (isl0 && (s + 1) < NS) xprefetch(s + 1);

        if (wg == 0) {
            // master: 4 waves poll all 256 per-WG flags (1 lane : 1 flag)
            if (tid < WGN) {
                while (__hip_atomic_load(&gflags[tid * 32], __ATOMIC_RELAXED,
                                         __HIP_MEMORY_SCOPE_AGENT) <= (unsigned int)(s + 1))
                    __builtin_amdgcn_s_sleep(1);
            }
            __syncthreads();   // all 256 arrivals observed
            if (tid < 16)      // broadcast tree: 16 gen copies, <=16 pollers each
                __hip_atomic_store(&gflags[GENB + tid * 32], (unsigned int)(s + 2),
                                   __ATOMIC_RELAXED, __HIP_MEMORY_SCOPE_AGENT);
        } else {
            if (tid == 0) {
                while (__hip_atomic_load(&gflags[GENB + (wg >> 4) * 32], __ATOMIC_RELAXED,
                                         __HIP_MEMORY_SCOPE_AGENT) <= (unsigned int)(s + 1))
                    __builtin_amdgcn_s_sleep(1);
            }
        }
        __syncthreads();   // gate: nobody stages before gen observed

        if (s == -1) {     // learn this XCD's WG count (tickets all taken pre-barrier)
            if (tid == 0)
                sh_tk[1] = (int)__hip_atomic_load(&gflags[CNTB + myxcd * 32],
                                                  __ATOMIC_RELAXED, __HIP_MEMORY_SCOPE_AGENT);
            __syncthreads();
            myT = sh_tk[1];
        }

        // ---- per-XCD staging: copy freshly-published slabs L3 -> local L2 mirror
        {
            int slabs[6]; int nslab = 0;
            if (s < 0) {
                slabs[0]=0; slabs[1]=1; slabs[2]=2; slabs[3]=3; slabs[4]=4; slabs[5]=5;
                nslab = 6;
            } else {
#pragma unroll
                for (int l = 0; l < NL; ++l) {
                    const int tl = s - l;
                    if (tl >= 0 && tl < NS) slabs[nslab++] = l * 2 + (tl & 1);
                }
            }
            const int nv = nslab << 13;                 // uint4 per slab = 8192
            for (int i = myticket * BLK + tid; i < nv; i += myT * BLK) {
                const int k = i >> 13;
                const size_t so = ((size_t)slabs[k] << 15) + (size_t)(i & 8191) * 4;
                const unsigned long long* sp = (const unsigned long long*)(act + so);
                const unsigned long long a = __hip_atomic_load(sp,     __ATOMIC_RELAXED, __HIP_MEMORY_SCOPE_AGENT);
                const unsigned long long b = __hip_atomic_load(sp + 1, __ATOMIC_RELAXED, __HIP_MEMORY_SCOPE_AGENT);
                *(unsigned long long*)(stageX + so)     = a;   // plain store -> local L2
                *(unsigned long long*)(stageX + so + 2) = b;
            }
        }
        __syncthreads();   // drains ALL waves' staging stores into L2

        // ---- XCD-local barrier + per-CU L1 flash inv ----
        if (tid == 0) {
            __hip_atomic_fetch_add(&gflags[XBARB + myxcd * 32], 1u,
                                   __ATOMIC_RELAXED, __HIP_MEMORY_SCOPE_AGENT);
            const unsigned target = (unsigned)myT * (unsigned)(s + 2);
            while (__hip_atomic_load(&gflags[XBARB + myxcd * 32], __ATOMIC_RELAXED,
                                     __HIP_MEMORY_SCOPE_AGENT) < target)
                __builtin_amdgcn_s_sleep(1);
            // L1-only flash inv: mirror addresses are rewritten every 2 steps,
            // stale L1 copies possible. L2 untouched (stays warm).
            asm volatile("buffer_inv\n\ts_waitcnt vmcnt(0)" ::: "memory");
            __builtin_amdgcn_sched_barrier(0);
        }
        __syncthreads();   // no wave issues next-step mirror loads before the inv
    }
}

// ---------------- fallback kernels (round-2, proven) ----------------
__global__ void init_kernel(const void* __restrict__ h0, float* __restrict__ st,
                            const int* __restrict__ flagp) {
    const int f32m = *flagp;
    const int idx = blockIdx.x * 256 + threadIdx.x;
    if (idx >= NL * NB * NH) return;
    const int l = idx >> 15;
    const int b = (idx >> 10) & 31;
    const int j = idx & 1023;
    const size_t src = (size_t)b * NL * NH + (size_t)l * NH + j;
    st[idx] = f32m ? ((const float*)h0)[src] : bf2f(((const unsigned short*)h0)[src]);
}

__global__ __launch_bounds__(256) void gru_layer(
    const void*  __restrict__ x,
    const float* __restrict__ inp,
    const float* __restrict__ hprev,
    float*       __restrict__ hnew,
    void*        __restrict__ h2out,
    const void* __restrict__ Wzi_, const void* __restrict__ Wzh_, const void* __restrict__ bzh_,
    const void* __restrict__ Wri_, const void* __restrict__ Wrh_, const void* __restrict__ brh_,
    const void* __restrict__ Wgi_, const void* __restrict__ Wgh_, const void* __restrict__ bgh_,
    const int* __restrict__ flagp, int tl, int isX)
{
    __shared__ float s_in[NB][129];
    __shared__ float s_h [NB][129];
    __shared__ float s_red[256][6];

    const int f32m = *flagp;
    const int t = tl & 0xFFFF;
    const int l = tl >> 16;
    const int tid = threadIdx.x;
    const int b   = tid & 31;
    const int jl  = (tid >> 5) & 1;
    const int ks  = tid >> 6;
    const int j   = blockIdx.x * 2 + jl;

    const size_t wIl = (size_t)l * NH * NI + (size_t)j * NI;
    const size_t bl  = (size_t)l * NH + j;

    float azi = 0.f, azh = 0.f, ari = 0.f, arh = 0.f, agi = 0.f, agh = 0.f;

    for (int kc = 0; kc < 8; ++kc) {
        const int k0 = kc * 128;
        __syncthreads();
        for (int idx = tid; idx < NB * 128; idx += 256) {
            const int r = idx >> 7, c = idx & 127;
            float vi;
            if (isX) {
                const size_t xo = (size_t)r * NS * NI + (size_t)t * NI + (k0 + c);
                vi = f32m ? ((const float*)x)[xo] : bf2f(((const unsigned short*)x)[xo]);
            } else {
                vi = inp[r * NH + k0 + c];
            }
            s_in[r][c] = vi;
            s_h [r][c] = hprev[r * NH + k0 + c];
        }
        __syncthreads();

        const int cbase = ks * 32;
#pragma unroll
        for (int q8 = 0; q8 < 4; ++q8) {
            const int c = cbase + q8 * 8;
            const int k = k0 + c;
            float wz[8], wr[8], wg[8], vz[8], vr[8], vg[8];
            if (f32m) {
                load8f((const float*)Wzi_ + wIl + k, wz);
                load8f((const float*)Wri_ + wIl + k, wr);
                load8f((const float*)Wgi_ + wIl + k, wg);
                load8f((const float*)Wzh_ + wIl + k, vz);
                load8f((const float*)Wrh_ + wIl + k, vr);
                load8f((const float*)Wgh_ + wIl + k, vg);
            } else {
                load8h((const unsigned short*)Wzi_ + wIl + k, wz);
                load8h((const unsigned short*)Wri_ + wIl + k, wr);
                load8h((const unsigned short*)Wgi_ + wIl + k, wg);
                load8h((const unsigned short*)Wzh_ + wIl + k, vz);
                load8h((const unsigned short*)Wrh_ + wIl + k, vr);
                load8h((const unsigned short*)Wgh_ + wIl + k, vg);
            }
            float ai[8], ah[8];
#pragma unroll
            for (int q = 0; q < 8; ++q) { ai[q] = s_in[b][c + q]; ah[q] = s_h[b][c + q]; }
#pragma unroll
            for (int q = 0; q < 8; ++q) {
                azi = fmaf(wz[q], ai[q], azi);
                ari = fmaf(wr[q], ai[q], ari);
                agi = fmaf(wg[q], ai[q], agi);
                azh = fmaf(vz[q], ah[q], azh);
                arh = fmaf(vr[q], ah[q], arh);
                agh = fmaf(vg[q], ah[q], agh);
            }
        }
    }

    s_red[tid][0] = azi; s_red[tid][1] = azh; s_red[tid][2] = ari;
    s_red[tid][3] = arh; s_red[tid][4] = agi; s_red[tid][5] = agh;
    __syncthreads();

    if (ks == 0) {
#pragma unroll
        for (int w = 1; w < 4; ++w) {
            azi += s_red[tid + 64*w][0]; azh += s_red[tid + 64*w][1];
            ari += s_red[tid + 64*w][2]; arh += s_red[tid + 64*w][3];
            agi += s_red[tid + 64*w][4]; agh += s_red[tid + 64*w][5];
        }
        const float bz = f32m ? ((const float*)bzh_)[bl] : bf2f(((const unsigned short*)bzh_)[bl]);
        const float br = f32m ? ((const float*)brh_)[bl] : bf2f(((const unsigned short*)brh_)[bl]);
        const float bg = f32m ? ((const float*)bgh_)[bl] : bf2f(((const unsigned short*)bgh_)[bl]);
        const float z = 1.f / (1.f + expf(-(azi + azh + bz)));
        const float r = 1.f / (1.f + expf(-(ari + arh + br)));
        const float g = tanhf(agi + r * (agh + bg));
        const float hp = hprev[b * NH + j];
        const float hn = z * hp + (1.f - z) * g;
        hnew[b * NH + j] = hn;
        if (h2out) {
            const size_t off = (size_t)b * NS * NO + (size_t)t * NO + j;
            if (f32m) ((float*)h2out)[off] = hn;
            else      ((unsigned short*)h2out)[off] = f2bf(hn);
        }
    }
}

__global__ __launch_bounds__(256) void out_gemm(
    void* __restrict__ out, const void* __restrict__ Wout, const void* __restrict__ bout,
    const int* __restrict__ flagp)
{
    __shared__ float s_a[8][1024];
    const int f32m = *flagp;
    const int tid = threadIdx.x;
    const size_t row0 = (size_t)blockIdx.x * 8;

    for (int idx = tid; idx < 8 * 1024; idx += 256) {
        const int r = idx >> 10, c = idx & 1023;
        const size_t off = (row0 + r) * NO + c;
        s_a[r][c] = f32m ? ((const float*)out)[off] : bf2f(((const unsigned short*)out)[off]);
    }
    __syncthreads();

    float acc[4][8];
#pragma unroll
    for (int m = 0; m < 4; ++m)
#pragma unroll
        for (int r = 0; r < 8; ++r) acc[m][r] = 0.f;

    for (int k8 = 0; k8 < 128; ++k8) {
        const int k = k8 * 8;
        float wf[4][8];
#pragma unroll
        for (int m = 0; m < 4; ++m) {
            const size_t wo = (size_t)(tid + 256*m) * NH + k;
            if (f32m) load8f((const float*)Wout + wo, wf[m]);
            else      load8h((const unsigned short*)Wout + wo, wf[m]);
        }
#pragma unroll
        for (int r = 0; r < 8; ++r) {
            float a[8];
#pragma unroll
            for (int q = 0; q < 8; ++q) a[q] = s_a[r][k + q];
#pragma unroll
            for (int m = 0; m < 4; ++m)
#pragma unroll
                for (int q = 0; q < 8; ++q)
                    acc[m][r] = fmaf(wf[m][q], a[q], acc[m][r]);
        }
    }

#pragma unroll
    for (int m = 0; m < 4; ++m) {
        const int jj = tid + 256*m;
        const float bj = f32m ? ((const float*)bout)[jj] : bf2f(((const unsigned short*)bout)[jj]);
#pragma unroll
        for (int r = 0; r < 8; ++r) {
            const size_t off = (row0 + r) * NO + jj;
            const float v = acc[m][r] + bj;
            if (f32m) ((float*)out)[off] = v;
            else      ((unsigned short*)out)[off] = f2bf(v);
        }
    }
}

__global__ void tail_kernel(const float* __restrict__ st, void* __restrict__ out,
                            const int* __restrict__ flagp)
{
    const int f32m = *flagp;
    const int idx = blockIdx.x * 256 + threadIdx.x;
    if (idx >= NL * NB * NH) return;
    const int l = idx >> 15;
    const int b = (idx >> 10) & 31;
    const int j = idx & 1023;
    const size_t dst = (size_t)NB * NS * NO + (size_t)b * NL * NH + (size_t)l * NH + j;
    if (f32m) ((float*)out)[dst] = st[idx];
    else      ((unsigned short*)out)[dst] = f2bf(st[idx]);
}

// ---------------- host ----------------
extern "C" void kernel_launch(void* const* d_in, const int* in_sizes, int n_in,
                              void* d_out, int out_size, void* d_ws, size_t ws_size,
                              hipStream_t stream)
{
    const void* x    = d_in[0];
    const void* h0   = d_in[1];
    const void* Wzi  = d_in[2];
    const void* Wzh  = d_in[3];
    const void* bzh  = d_in[4];
    const void* Wri  = d_in[5];
    const void* Wrh  = d_in[6];
    const void* brh  = d_in[7];
    const void* Wgi  = d_in[8];
    const void* Wgh  = d_in[9];
    const void* bgh  = d_in[10];
    const void* Wout = d_in[11];
    const void* bout = d_in[12];

    // ws layout
    char* w = (char*)d_ws;
    float* st            = (float*)w;                       // [2][3][32][1024] f32
    int*   flag          = (int*)(w + 786432);
    unsigned int* act    = (unsigned int*)(w + 786464);     // [3][2][32][1024] packed hi|lo
    unsigned int* gflags = (unsigned int*)(w + 1572992);    // GFL_N dwords
    unsigned int* stage  = (unsigned int*)(w + 2097152);    // 8 XCD x 768 KB mirror -> ends 8 MB
    auto stp = [&](int p, int l) { return st + ((size_t)(p * NL + l)) * NB * NH; };

    detect_kernel<<<1, 256, 0, stream>>>((const unsigned int*)x, flag);
    init_act<<<(NL*NB*NH + 255)/256, 256, 0, stream>>>(h0, act, gflags, flag);

    const bool ws_ok = (ws_size == 0) /* unknown: assume big */ || (ws_size >= 8912896);
    hipError_t perr = hipSuccess;
    if (ws_ok) {
        (void)hipFuncSetAttribute((const void*)&gru_persist<1>,
                                  hipFuncAttributeMaxDynamicSharedMemorySize, LDSB);
        (void)hipFuncSetAttribute((const void*)&gru_persist<0>,
                                  hipFuncAttributeMaxDynamicSharedMemorySize, LDSB);
        (void)hipGetLastError();   // clear
        gru_persist<1><<<WGN, BLK, LDSB, stream>>>(
            x, Wzi, Wzh, bzh, Wri, Wrh, brh, Wgi, Wgh, bgh,
            d_out, act, stage, st, flag, gflags);
        gru_persist<0><<<WGN, BLK, LDSB, stream>>>(
            x, Wzi, Wzh, bzh, Wri, Wrh, brh, Wgi, Wgh, bgh,
            d_out, act, stage, st, flag, gflags);
        perr = hipGetLastError();
    }

    if (!ws_ok || perr != hipSuccess) {
        init_kernel<<<(NL*NB*NH + 255)/256, 256, 0, stream>>>(h0, st, flag);
        for (int t = 0; t < NS; ++t) {
            const int pr = t & 1, pw = 1 - pr;
            for (int l = 0; l < NL; ++l) {
                gru_layer<<<512, 256, 0, stream>>>(
                    x,
                    l == 0 ? st : stp(pw, l - 1),
                    stp(pr, l),
                    stp(pw, l),
                    l == 2 ? d_out : (void*)nullptr,
                    Wzi, Wzh, bzh, Wri, Wrh, brh, Wgi, Wgh, bgh,
                    flag, t | (l << 16), l == 0 ? 1 : 0);
            }
        }
    }

    out_gemm<<<NB * NS / 8, 256, 0, stream>>>(d_out, Wout, bout, flag);
    tail_kernel<<<(NL*NB*NH + 255)/256, 256, 0, stream>>>(st, d_out, flag);
}